// Round 2
// baseline (274.237 us; speedup 1.0000x reference)
//
#include <hip/hip_runtime.h>
#include <stdint.h>

#define SEQ   2048
#define NDIM  1024
#define NH    16
#define HD    64
#define KDIM  1024

typedef short  short8  __attribute__((ext_vector_type(8)));
typedef float  floatx4 __attribute__((ext_vector_type(4)));
typedef float  floatx16 __attribute__((ext_vector_type(16)));
typedef unsigned short ushort4v __attribute__((ext_vector_type(4)));
typedef _Float16 half8 __attribute__((ext_vector_type(8)));
typedef __fp16  fp16x2 __attribute__((ext_vector_type(2)));
typedef unsigned int uint2v __attribute__((ext_vector_type(2)));
typedef unsigned int uint4v __attribute__((ext_vector_type(4)));

typedef __attribute__((address_space(1))) void GV;   // global AS
typedef __attribute__((address_space(3))) void LV;   // LDS AS

#define QSCALE 0.04508422003f   // log2(e)/32  (folded into Q at GEMM1 epilogue)

__device__ __forceinline__ unsigned short f2bf(float f) {
    unsigned int u = __float_as_uint(f);
    u += 0x7fffu + ((u >> 16) & 1u);     // round-to-nearest-even
    return (unsigned short)(u >> 16);
}

__device__ __forceinline__ float ex2(float x) {
#if __has_builtin(__builtin_amdgcn_exp2f)
    return __builtin_amdgcn_exp2f(x);    // bare v_exp_f32, no libm fixup
#else
    return exp2f(x);
#endif
}

// exchange upper half of a with lower half of b (v_permlane32_swap_b32)
__device__ __forceinline__ void pl32swap(unsigned int &a, unsigned int &b) {
#if __has_builtin(__builtin_amdgcn_permlane32_swap)
    uint2v r = __builtin_amdgcn_permlane32_swap(a, b, false, false);
    a = r.x; b = r.y;
#else
    asm("v_permlane32_swap_b32 %0, %1" : "+v"(a), "+v"(b));
#endif
}

// ---------------------------------------------------------------- cast kernel
__global__ __launch_bounds__(256) void cast_f32_bf16(const float* __restrict__ in,
                                                     unsigned short* __restrict__ out) {
    int i = (blockIdx.x * 256 + threadIdx.x) * 4;
    float4 v = *(const float4*)(in + i);
    ushort4v o;
    o.x = f2bf(v.x); o.y = f2bf(v.y); o.z = f2bf(v.z); o.w = f2bf(v.w);
    *(ushort4v*)(out + i) = o;
}

// ---------------------------------------------------------------- GEMM (C = A * B^T), bf16 in, fp32 acc
// async double-buffered staging — ONE barrier per K-tile.
// MODE 0: qkv scatter epilogue. Q: row-major pre-scaled bf16.
//   K/V: 32x32x16 MFMA fragment order per 64-key subtile (4096 ushorts):
//   K slot(kt,ks)=kt*4+ks, addr=((slot*64+lane)*8+e): K[key=kt*32+(lane&31)][hd=ks*16+(lane>>5)*8+e]  (bf16)
//   V slot(ht,kc)=ht*4+kc, addr=((slot*64+lane)*8+e): V[key=kc*16+(lane>>5)*8+e][hd=ht*32+(lane&31)]  (fp16)
// MODE 1: fp32 out + bias epilogue
template<int MODE>
__global__ __launch_bounds__(256, 3)
void gemm_bt(const unsigned short* __restrict__ A,
             const unsigned short* __restrict__ B,
             unsigned short* __restrict__ Cq,
             unsigned short* __restrict__ Ck,
             unsigned short* __restrict__ Cv,
             const float* __restrict__ bias,
             float* __restrict__ Cout)
{
    __shared__ unsigned short As[2][4096];
    __shared__ unsigned short Bs[2][4096];
    const int tid  = threadIdx.x;
    const int lane = tid & 63;
    const int w    = tid >> 6;
    const int quad = lane >> 4;
    const int l15  = lane & 15;
    const int wm   = w >> 1, wn = w & 1;
    const int bm   = blockIdx.x, bn = blockIdx.y;

    const unsigned short* Arow = A + (size_t)bm * 128 * KDIM;
    const unsigned short* Brow = B + (size_t)bn * 128 * KDIM;

    const unsigned short* ga[2]; const unsigned short* gb[2];
    unsigned short* la[2][2];    unsigned short* lb[2][2];
#pragma unroll
    for (int i = 0; i < 2; ++i) {
        int j = ((w * 2 + i) << 6) + lane;
        int r = j >> 2;
        int c = (j & 3) ^ ((r >> 1) & 3);
        ga[i] = Arow + r * KDIM + c * 8;
        gb[i] = Brow + r * KDIM + c * 8;
#pragma unroll
        for (int b = 0; b < 2; ++b) {
            la[b][i] = &As[b][(w * 2 + i) << 9];
            lb[b][i] = &Bs[b][(w * 2 + i) << 9];
        }
    }

    int achunk[4], bchunk[4];
#pragma unroll
    for (int t = 0; t < 4; ++t) {
        int ra = wm * 64 + t * 16 + l15;
        achunk[t] = (ra << 2) + (quad ^ ((ra >> 1) & 3));
        int rb = wn * 64 + t * 16 + l15;
        bchunk[t] = (rb << 2) + (quad ^ ((rb >> 1) & 3));
    }

    floatx4 acc[4][4];
#pragma unroll
    for (int mt = 0; mt < 4; ++mt)
#pragma unroll
        for (int nt = 0; nt < 4; ++nt)
            acc[mt][nt] = (floatx4){0.f, 0.f, 0.f, 0.f};

    // prologue: DMA K-tile 0 into buffer 0
#pragma unroll
    for (int i = 0; i < 2; ++i) {
        __builtin_amdgcn_global_load_lds((GV*)(void*)ga[i], (LV*)(void*)la[0][i], 16, 0, 0);
        __builtin_amdgcn_global_load_lds((GV*)(void*)gb[i], (LV*)(void*)lb[0][i], 16, 0, 0);
    }

    for (int kt = 0; kt < KDIM / 32; ++kt) {
        const int buf = kt & 1;
        __syncthreads();   // drains DMA for buf (issued a full compute phase ago)
        if (kt < KDIM / 32 - 1) {
#pragma unroll
            for (int i = 0; i < 2; ++i) {
                __builtin_amdgcn_global_load_lds((GV*)(void*)(ga[i] + (kt + 1) * 32), (LV*)(void*)la[buf ^ 1][i], 16, 0, 0);
                __builtin_amdgcn_global_load_lds((GV*)(void*)(gb[i] + (kt + 1) * 32), (LV*)(void*)lb[buf ^ 1][i], 16, 0, 0);
            }
        }
        short8 af[4], bf[4];
#pragma unroll
        for (int t = 0; t < 4; ++t) {
            af[t] = *(const short8*)(&As[buf][0] + (achunk[t] << 3));
            bf[t] = *(const short8*)(&Bs[buf][0] + (bchunk[t] << 3));
        }
#pragma unroll
        for (int mt = 0; mt < 4; ++mt)
#pragma unroll
            for (int nt = 0; nt < 4; ++nt)
                acc[mt][nt] = __builtin_amdgcn_mfma_f32_16x16x32_bf16(af[mt], bf[nt], acc[mt][nt], 0, 0, 0);
    }

    if (MODE == 0) {
        const int which = bn >> 3;  // 0=q 1=k 2=v
        unsigned short* dst = which == 0 ? Cq : (which == 1 ? Ck : Cv);
        if (which == 2) {
            // V: fp16, 32x32 fragment order; r=0..3 are consecutive elems e
#pragma unroll
            for (int nt = 0; nt < 4; ++nt) {
                int e0   = ((bn & 7) << 7) + wn * 64 + nt * 16;
                int head = e0 >> 6;
                int hd   = (e0 & 63) + l15;
#pragma unroll
                for (int mt = 0; mt < 4; ++mt) {
                    int n0 = bm * 128 + wm * 64 + mt * 16 + quad * 4;
                    int b  = n0 >> 11;
                    int n  = n0 & 2047;
                    int bh = (b << 4) + head;
                    size_t base = (size_t)bh * 131072
                                + (size_t)(n >> 6) * 4096
                                + (size_t)((((hd >> 5) << 2) + ((n >> 4) & 3)) << 9)
                                + ((((n >> 3) & 1) << 5) + (hd & 31)) * 8
                                + (n & 7);
                    fp16x2 p01 = __builtin_amdgcn_cvt_pkrtz(acc[mt][nt][0], acc[mt][nt][1]);
                    fp16x2 p23 = __builtin_amdgcn_cvt_pkrtz(acc[mt][nt][2], acc[mt][nt][3]);
                    uint2v st;
                    st.x = __builtin_bit_cast(unsigned int, p01);
                    st.y = __builtin_bit_cast(unsigned int, p23);
                    *(uint2v*)(dst + base) = st;
                }
            }
        } else {
#pragma unroll
            for (int nt = 0; nt < 4; ++nt) {
                int e0   = ((bn & 7) << 7) + wn * 64 + nt * 16;
                int head = e0 >> 6;
                int hd   = (e0 & 63) + l15;
#pragma unroll
                for (int mt = 0; mt < 4; ++mt) {
#pragma unroll
                    for (int r = 0; r < 4; ++r) {
                        int m = bm * 128 + wm * 64 + mt * 16 + quad * 4 + r;
                        int b = m >> 11, n = m & 2047;
                        int bh = (b << 4) + head;
                        float val = acc[mt][nt][r];
                        if (which == 0) {
                            dst[((size_t)bh * SEQ + n) * HD + hd] = f2bf(val * QSCALE);
                        } else {
                            size_t idx = (size_t)bh * 131072
                                       + (size_t)(n >> 6) * 4096
                                       + (size_t)(((((n >> 5) & 1) << 2) + (hd >> 4)) << 9)
                                       + ((((hd >> 3) & 1) << 5) + (n & 31)) * 8
                                       + (hd & 7);
                            dst[idx] = f2bf(val);
                        }
                    }
                }
            }
        }
    } else {
#pragma unroll
        for (int nt = 0; nt < 4; ++nt) {
            int e = bn * 128 + wn * 64 + nt * 16 + l15;
            float bv = bias[e];
#pragma unroll
            for (int mt = 0; mt < 4; ++mt) {
#pragma unroll
                for (int r = 0; r < 4; ++r) {
                    int m = bm * 128 + wm * 64 + mt * 16 + quad * 4 + r;
                    Cout[(size_t)m * NDIM + e] = acc[mt][nt][r] + bv;
                }
            }
        }
    }
}

// ---------------------------------------------------------------- flash attention, v8
// v8: 32x32x16 MFMA. v7 post-mortem: LDS-read-bound (4.3 GB LDS traffic =
// 91 B/cyc/CU = ds_read_b128 ceiling). 32x32x16 reads the same 16B/lane
// per MFMA but does 2x the FLOPs -> LDS bytes/FLOP halved, and the 32x32
// pipe is ~15% faster than 16x16 (2382 vs 2075 TF).
// Structure: 4 waves x 32 q-rows = 128 q/block, 1024 blocks.
//   QK: S^T(32k x 32q) = mfma_32x32x16_bf16(A=K-frag, B=Q-frag)
//   P^T C-layout -> B-frag via cvt_pkrtz + v_permlane32_swap_b32 (T12)
//   PV: O^T(32hd x 32q) = mfma_32x32x16_f16(A=V^T-frag, B=P^T-frag)
//   l: in-lane f32 adds (drops the l-MFMAs), cross-half shfl_xor at epilogue.
__global__ __launch_bounds__(256, 4)
void attn_fused(const unsigned short* __restrict__ qb,
                const unsigned short* __restrict__ kfrag,   // bf16 fragment-order
                const unsigned short* __restrict__ vfrag,   // fp16 fragment-order
                unsigned short* __restrict__ ob)            // bf16 [b][n][1024]
{
    __shared__ unsigned short Ks[2][4096];   // 64-key K subtile x2 (16 KB)
    __shared__ unsigned short Vs[2][4096];   // 64-key V subtile x2 (16 KB)

    const int tid  = threadIdx.x;
    const int lane = tid & 63;
    const int w    = tid >> 6;              // 0..3
    const int l31  = lane & 31;
    const int half = lane >> 5;

    const int bid  = blockIdx.x;
    const int xcd  = bid & 7;
    const int slot = bid >> 3;
    const int bh   = xcd * 8 + (slot >> 4);   // 8 bh per XCD
    const int q0   = (slot & 15) * 128;

    const unsigned short* Qb = qb    + (size_t)bh * SEQ * HD;
    const unsigned short* Kb = kfrag + (size_t)bh * 131072;
    const unsigned short* Vb = vfrag + (size_t)bh * 131072;

    // Q fragments (B operand 32x32x16): col=q=lane&31, k=(lane>>5)*8+e; pre-scaled
    short8 qf[4];
    {
        const unsigned short* qrow = Qb + (size_t)(q0 + w * 32 + l31) * HD + half * 8;
#pragma unroll
        for (int ks = 0; ks < 4; ++ks)
            qf[ks] = *(const short8*)(qrow + ks * 16);
    }

    floatx16 oacc[2];   // O^T: col=q=lane&31, row=hd_local=(reg&3)+8*(reg>>2)+4*half
#pragma unroll
    for (int ht = 0; ht < 2; ++ht)
#pragma unroll
        for (int i = 0; i < 16; ++i) oacc[ht][i] = 0.f;
    float lp0 = 0.f, lp1 = 0.f, lp2 = 0.f, lp3 = 0.f;

    // staging: 8 thread-chunks x 64 lanes x 16B = 8KB per subtile (K and V)
    const unsigned short* gk[2]; const unsigned short* gv[2];
    unsigned short* lk[2][2];    unsigned short* lv[2][2];
#pragma unroll
    for (int i = 0; i < 2; ++i) {
        int off = (((w * 2 + i) << 6) + lane) * 8;
        gk[i] = Kb + off;
        gv[i] = Vb + off;
#pragma unroll
        for (int b = 0; b < 2; ++b) {
            lk[b][i] = &Ks[b][(w * 2 + i) << 9];
            lv[b][i] = &Vs[b][(w * 2 + i) << 9];
        }
    }

    // prologue: DMA subtile 0 into buffer 0
#pragma unroll
    for (int i = 0; i < 2; ++i) {
        __builtin_amdgcn_global_load_lds((GV*)(void*)gk[i], (LV*)(void*)lk[0][i], 16, 0, 0);
        __builtin_amdgcn_global_load_lds((GV*)(void*)gv[i], (LV*)(void*)lv[0][i], 16, 0, 0);
    }

    for (int t = 0; t < 32; ++t) {
        const int buf = t & 1;
        __syncthreads();
        if (t < 31) {
#pragma unroll
            for (int i = 0; i < 2; ++i) {
                __builtin_amdgcn_global_load_lds((GV*)(void*)(gk[i] + (t + 1) * 4096), (LV*)(void*)lk[buf ^ 1][i], 16, 0, 0);
                __builtin_amdgcn_global_load_lds((GV*)(void*)(gv[i] + (t + 1) * 4096), (LV*)(void*)lv[buf ^ 1][i], 16, 0, 0);
            }
        }
        const unsigned short* KsB = Ks[buf];
        const unsigned short* VsB = Vs[buf];

#pragma unroll
        for (int kt = 0; kt < 2; ++kt) {
            // ---- S^T(32k x 32q) over hd=64
            floatx16 s;
#pragma unroll
            for (int i = 0; i < 16; ++i) s[i] = 0.f;
            __builtin_amdgcn_s_setprio(1);
#pragma unroll
            for (int ks = 0; ks < 4; ++ks) {
                short8 kf = *(const short8*)(KsB + ((kt * 4 + ks) << 9) + lane * 8);
                s = __builtin_amdgcn_mfma_f32_32x32x16_bf16(kf, qf[ks], s, 0, 0, 0);
            }
            __builtin_amdgcn_s_setprio(0);

            // ---- softmax: exp2, l-partials, pack f16, half-swap into B-frags
            float e[16];
#pragma unroll
            for (int i = 0; i < 16; ++i) e[i] = ex2(s[i]);
            lp0 += (e[0] + e[1]) + (e[2] + e[3]);
            lp1 += (e[4] + e[5]) + (e[6] + e[7]);
            lp2 += (e[8] + e[9]) + (e[10] + e[11]);
            lp3 += (e[12] + e[13]) + (e[14] + e[15]);
            unsigned int u[8];
#pragma unroll
            for (int j = 0; j < 8; ++j) {
                fp16x2 p = __builtin_amdgcn_cvt_pkrtz(e[2 * j], e[2 * j + 1]);
                u[j] = __builtin_bit_cast(unsigned int, p);
            }
            pl32swap(u[0], u[2]); pl32swap(u[1], u[3]);
            pl32swap(u[4], u[6]); pl32swap(u[5], u[7]);
            half8 pb0, pb1;
            { uint4v t0; t0.x = u[0]; t0.y = u[1]; t0.z = u[2]; t0.w = u[3];
              pb0 = __builtin_bit_cast(half8, t0); }
            { uint4v t1; t1.x = u[4]; t1.y = u[5]; t1.z = u[6]; t1.w = u[7];
              pb1 = __builtin_bit_cast(half8, t1); }

            // ---- PV: O^T += V^T * P^T
            __builtin_amdgcn_s_setprio(1);
#pragma unroll
            for (int ht = 0; ht < 2; ++ht) {
                uint4v v0 = *(const uint4v*)(VsB + (((ht << 2) + kt * 2) << 9) + lane * 8);
                uint4v v1 = *(const uint4v*)(VsB + (((ht << 2) + kt * 2 + 1) << 9) + lane * 8);
                oacc[ht] = __builtin_amdgcn_mfma_f32_32x32x16_f16(__builtin_bit_cast(half8, v0), pb0, oacc[ht], 0, 0, 0);
                oacc[ht] = __builtin_amdgcn_mfma_f32_32x32x16_f16(__builtin_bit_cast(half8, v1), pb1, oacc[ht], 0, 0, 0);
            }
            __builtin_amdgcn_s_setprio(0);
        }
    }

    // ---- epilogue: l across lane halves, O /= l, write bf16
    float lfull = (lp0 + lp1) + (lp2 + lp3);
    lfull += __shfl_xor(lfull, 32);
    float inv = 1.f / lfull;
    const int b = bh >> 4, h = bh & 15;
    const int qg = q0 + w * 32 + l31;
    unsigned short* orow = ob + ((size_t)b * SEQ + qg) * NDIM + h * HD;
#pragma unroll
    for (int ht = 0; ht < 2; ++ht) {
#pragma unroll
        for (int g = 0; g < 4; ++g) {
            int hd0 = ht * 32 + g * 8 + half * 4;
            unsigned int w0 = (unsigned int)f2bf(oacc[ht][g * 4 + 0] * inv)
                            | ((unsigned int)f2bf(oacc[ht][g * 4 + 1] * inv) << 16);
            unsigned int w1 = (unsigned int)f2bf(oacc[ht][g * 4 + 2] * inv)
                            | ((unsigned int)f2bf(oacc[ht][g * 4 + 3] * inv) << 16);
            uint2v st; st.x = w0; st.y = w1;
            *(uint2v*)(orow + hd0) = st;
        }
    }
}

// ---------------------------------------------------------------- launch
extern "C" void kernel_launch(void* const* d_in, const int* in_sizes, int n_in,
                              void* d_out, int out_size, void* d_ws, size_t ws_size,
                              hipStream_t stream)
{
    (void)in_sizes; (void)n_in; (void)out_size; (void)ws_size;
    const float* x    = (const float*)d_in[0];
    const float* wqkv = (const float*)d_in[1];
    const float* wout = (const float*)d_in[2];
    const float* bout = (const float*)d_in[3];
    float* out = (float*)d_out;

    unsigned short* xb    = (unsigned short*)d_ws;
    unsigned short* wqkvb = xb    + 8388608;
    unsigned short* woutb = wqkvb + 3145728;
    unsigned short* qbuf  = woutb + 1048576;
    unsigned short* kbuf  = qbuf  + 8388608;
    unsigned short* vbuf  = kbuf  + 8388608;
    unsigned short* obuf  = vbuf  + 8388608;

    cast_f32_bf16<<<8192, 256, 0, stream>>>(x, xb);
    cast_f32_bf16<<<3072, 256, 0, stream>>>(wqkv, wqkvb);
    cast_f32_bf16<<<1024, 256, 0, stream>>>(wout, woutb);

    gemm_bt<0><<<dim3(64, 24), 256, 0, stream>>>(xb, wqkvb, qbuf, kbuf, vbuf, nullptr, nullptr);
    attn_fused<<<1024, 256, 0, stream>>>(qbuf, kbuf, vbuf, obuf);
    gemm_bt<1><<<dim3(64, 8), 256, 0, stream>>>(obuf, woutb, nullptr, nullptr, nullptr, bout, out);
}

// Round 3
// 257.310 us; speedup vs baseline: 1.0658x; 1.0658x over previous
//
#include <hip/hip_runtime.h>
#include <stdint.h>

#define SEQ   2048
#define NDIM  1024
#define NH    16
#define HD    64
#define KDIM  1024

typedef short  short8  __attribute__((ext_vector_type(8)));
typedef float  floatx4 __attribute__((ext_vector_type(4)));
typedef float  floatx16 __attribute__((ext_vector_type(16)));
typedef unsigned short ushort4v __attribute__((ext_vector_type(4)));
typedef _Float16 half8 __attribute__((ext_vector_type(8)));
typedef __fp16  fp16x2 __attribute__((ext_vector_type(2)));
typedef unsigned int uint2v __attribute__((ext_vector_type(2)));
typedef unsigned int uint4v __attribute__((ext_vector_type(4)));

typedef __attribute__((address_space(1))) void GV;   // global AS
typedef __attribute__((address_space(3))) void LV;   // LDS AS

#define QSCALE 0.04508422003f   // log2(e)/32  (folded into Q at GEMM1 epilogue)

__device__ __forceinline__ unsigned short f2bf(float f) {
    unsigned int u = __float_as_uint(f);
    u += 0x7fffu + ((u >> 16) & 1u);     // round-to-nearest-even
    return (unsigned short)(u >> 16);
}

__device__ __forceinline__ float ex2(float x) {
#if __has_builtin(__builtin_amdgcn_exp2f)
    return __builtin_amdgcn_exp2f(x);    // bare v_exp_f32, no libm fixup
#else
    return exp2f(x);
#endif
}

// exchange upper half of a with lower half of b (v_permlane32_swap_b32)
__device__ __forceinline__ void pl32swap(unsigned int &a, unsigned int &b) {
#if __has_builtin(__builtin_amdgcn_permlane32_swap)
    uint2v r = __builtin_amdgcn_permlane32_swap(a, b, false, false);
    a = r.x; b = r.y;
#else
    asm("v_permlane32_swap_b32 %0, %1" : "+v"(a), "+v"(b));
#endif
}

// ---------------------------------------------------------------- cast kernel
__global__ __launch_bounds__(256) void cast_f32_bf16(const float* __restrict__ in,
                                                     unsigned short* __restrict__ out) {
    int i = (blockIdx.x * 256 + threadIdx.x) * 4;
    float4 v = *(const float4*)(in + i);
    ushort4v o;
    o.x = f2bf(v.x); o.y = f2bf(v.y); o.z = f2bf(v.z); o.w = f2bf(v.w);
    *(ushort4v*)(out + i) = o;
}

// ---------------------------------------------------------------- GEMM (C = A * B^T), bf16 in, fp32 acc
// async double-buffered staging — ONE barrier per K-tile.
// MODE 0: qkv scatter epilogue. Q: row-major pre-scaled bf16.
//   K/V: 32x32x16 MFMA fragment order per 64-key subtile (4096 ushorts):
//   K slot(kt,ks)=kt*4+ks, addr=((slot*64+lane)*8+e): K[key=kt*32+(lane&31)][hd=ks*16+(lane>>5)*8+e]  (bf16)
//   V slot(ht,kc)=ht*4+kc, addr=((slot*64+lane)*8+e): V[key=kc*16+(lane>>5)*8+e][hd=ht*32+(lane&31)]  (fp16)
// MODE 1: fp32 out + bias epilogue
template<int MODE>
__global__ __launch_bounds__(256, 3)
void gemm_bt(const unsigned short* __restrict__ A,
             const unsigned short* __restrict__ B,
             unsigned short* __restrict__ Cq,
             unsigned short* __restrict__ Ck,
             unsigned short* __restrict__ Cv,
             const float* __restrict__ bias,
             float* __restrict__ Cout)
{
    __shared__ unsigned short As[2][4096];
    __shared__ unsigned short Bs[2][4096];
    const int tid  = threadIdx.x;
    const int lane = tid & 63;
    const int w    = tid >> 6;
    const int quad = lane >> 4;
    const int l15  = lane & 15;
    const int wm   = w >> 1, wn = w & 1;
    const int bm   = blockIdx.x, bn = blockIdx.y;

    const unsigned short* Arow = A + (size_t)bm * 128 * KDIM;
    const unsigned short* Brow = B + (size_t)bn * 128 * KDIM;

    const unsigned short* ga[2]; const unsigned short* gb[2];
    unsigned short* la[2][2];    unsigned short* lb[2][2];
#pragma unroll
    for (int i = 0; i < 2; ++i) {
        int j = ((w * 2 + i) << 6) + lane;
        int r = j >> 2;
        int c = (j & 3) ^ ((r >> 1) & 3);
        ga[i] = Arow + r * KDIM + c * 8;
        gb[i] = Brow + r * KDIM + c * 8;
#pragma unroll
        for (int b = 0; b < 2; ++b) {
            la[b][i] = &As[b][(w * 2 + i) << 9];
            lb[b][i] = &Bs[b][(w * 2 + i) << 9];
        }
    }

    int achunk[4], bchunk[4];
#pragma unroll
    for (int t = 0; t < 4; ++t) {
        int ra = wm * 64 + t * 16 + l15;
        achunk[t] = (ra << 2) + (quad ^ ((ra >> 1) & 3));
        int rb = wn * 64 + t * 16 + l15;
        bchunk[t] = (rb << 2) + (quad ^ ((rb >> 1) & 3));
    }

    floatx4 acc[4][4];
#pragma unroll
    for (int mt = 0; mt < 4; ++mt)
#pragma unroll
        for (int nt = 0; nt < 4; ++nt)
            acc[mt][nt] = (floatx4){0.f, 0.f, 0.f, 0.f};

    // prologue: DMA K-tile 0 into buffer 0
#pragma unroll
    for (int i = 0; i < 2; ++i) {
        __builtin_amdgcn_global_load_lds((GV*)(void*)ga[i], (LV*)(void*)la[0][i], 16, 0, 0);
        __builtin_amdgcn_global_load_lds((GV*)(void*)gb[i], (LV*)(void*)lb[0][i], 16, 0, 0);
    }

    for (int kt = 0; kt < KDIM / 32; ++kt) {
        const int buf = kt & 1;
        __syncthreads();   // drains DMA for buf (issued a full compute phase ago)
        if (kt < KDIM / 32 - 1) {
#pragma unroll
            for (int i = 0; i < 2; ++i) {
                __builtin_amdgcn_global_load_lds((GV*)(void*)(ga[i] + (kt + 1) * 32), (LV*)(void*)la[buf ^ 1][i], 16, 0, 0);
                __builtin_amdgcn_global_load_lds((GV*)(void*)(gb[i] + (kt + 1) * 32), (LV*)(void*)lb[buf ^ 1][i], 16, 0, 0);
            }
        }
        short8 af[4], bf[4];
#pragma unroll
        for (int t = 0; t < 4; ++t) {
            af[t] = *(const short8*)(&As[buf][0] + (achunk[t] << 3));
            bf[t] = *(const short8*)(&Bs[buf][0] + (bchunk[t] << 3));
        }
#pragma unroll
        for (int mt = 0; mt < 4; ++mt)
#pragma unroll
            for (int nt = 0; nt < 4; ++nt)
                acc[mt][nt] = __builtin_amdgcn_mfma_f32_16x16x32_bf16(af[mt], bf[nt], acc[mt][nt], 0, 0, 0);
    }

    if (MODE == 0) {
        const int which = bn >> 3;  // 0=q 1=k 2=v
        unsigned short* dst = which == 0 ? Cq : (which == 1 ? Ck : Cv);
        if (which == 2) {
            // V: fp16, 32x32 fragment order; r=0..3 are consecutive elems e
#pragma unroll
            for (int nt = 0; nt < 4; ++nt) {
                int e0   = ((bn & 7) << 7) + wn * 64 + nt * 16;
                int head = e0 >> 6;
                int hd   = (e0 & 63) + l15;
#pragma unroll
                for (int mt = 0; mt < 4; ++mt) {
                    int n0 = bm * 128 + wm * 64 + mt * 16 + quad * 4;
                    int b  = n0 >> 11;
                    int n  = n0 & 2047;
                    int bh = (b << 4) + head;
                    size_t base = (size_t)bh * 131072
                                + (size_t)(n >> 6) * 4096
                                + (size_t)((((hd >> 5) << 2) + ((n >> 4) & 3)) << 9)
                                + ((((n >> 3) & 1) << 5) + (hd & 31)) * 8
                                + (n & 7);
                    fp16x2 p01 = __builtin_amdgcn_cvt_pkrtz(acc[mt][nt][0], acc[mt][nt][1]);
                    fp16x2 p23 = __builtin_amdgcn_cvt_pkrtz(acc[mt][nt][2], acc[mt][nt][3]);
                    uint2v st;
                    st.x = __builtin_bit_cast(unsigned int, p01);
                    st.y = __builtin_bit_cast(unsigned int, p23);
                    *(uint2v*)(dst + base) = st;
                }
            }
        } else {
#pragma unroll
            for (int nt = 0; nt < 4; ++nt) {
                int e0   = ((bn & 7) << 7) + wn * 64 + nt * 16;
                int head = e0 >> 6;
                int hd   = (e0 & 63) + l15;
#pragma unroll
                for (int mt = 0; mt < 4; ++mt) {
#pragma unroll
                    for (int r = 0; r < 4; ++r) {
                        int m = bm * 128 + wm * 64 + mt * 16 + quad * 4 + r;
                        int b = m >> 11, n = m & 2047;
                        int bh = (b << 4) + head;
                        float val = acc[mt][nt][r];
                        if (which == 0) {
                            dst[((size_t)bh * SEQ + n) * HD + hd] = f2bf(val * QSCALE);
                        } else {
                            size_t idx = (size_t)bh * 131072
                                       + (size_t)(n >> 6) * 4096
                                       + (size_t)(((((n >> 5) & 1) << 2) + (hd >> 4)) << 9)
                                       + ((((hd >> 3) & 1) << 5) + (n & 31)) * 8
                                       + (hd & 7);
                            dst[idx] = f2bf(val);
                        }
                    }
                }
            }
        }
    } else {
#pragma unroll
        for (int nt = 0; nt < 4; ++nt) {
            int e = bn * 128 + wn * 64 + nt * 16 + l15;
            float bv = bias[e];
#pragma unroll
            for (int mt = 0; mt < 4; ++mt) {
#pragma unroll
                for (int r = 0; r < 4; ++r) {
                    int m = bm * 128 + wm * 64 + mt * 16 + quad * 4 + r;
                    Cout[(size_t)m * NDIM + e] = acc[mt][nt][r] + bv;
                }
            }
        }
    }
}

// ---------------------------------------------------------------- flash attention, v9
// v9: amortize LDS reads over TWO 32-q tiles per wave. v8 post-mortem: the
// binding resource is ds_read_b128 issue bandwidth at the CU (per-CU LDS
// cycles: v7 82us, v8 41us — matches measured durations). Each K/V fragment
// read from LDS now feeds 2 MFMAs (q-tile A and B) -> LDS traffic halves
// again (~20.5us/CU floor). Two independent QK chains + paired A/B softmax
// give in-wave ILP, so overlap no longer depends on occupancy (8 waves/CU
// at ~170 regs/wave; launch_bounds(256,2) to avoid spills).
// 4 waves x 64 q-rows = 256 q/block, 512 blocks.
__global__ __launch_bounds__(256, 2)
void attn_fused(const unsigned short* __restrict__ qb,
                const unsigned short* __restrict__ kfrag,   // bf16 fragment-order
                const unsigned short* __restrict__ vfrag,   // fp16 fragment-order
                unsigned short* __restrict__ ob)            // bf16 [b][n][1024]
{
    __shared__ unsigned short Ks[2][4096];   // 64-key K subtile x2 (16 KB)
    __shared__ unsigned short Vs[2][4096];   // 64-key V subtile x2 (16 KB)

    const int tid  = threadIdx.x;
    const int lane = tid & 63;
    const int w    = tid >> 6;              // 0..3
    const int l31  = lane & 31;
    const int half = lane >> 5;

    const int bid  = blockIdx.x;            // 512 blocks
    const int xcd  = bid & 7;
    const int slot = bid >> 3;              // 0..63
    const int bh   = xcd * 8 + (slot >> 3); // 8 bh per XCD
    const int q0   = (slot & 7) * 256;

    const unsigned short* Qb = qb    + (size_t)bh * SEQ * HD;
    const unsigned short* Kb = kfrag + (size_t)bh * 131072;
    const unsigned short* Vb = vfrag + (size_t)bh * 131072;

    // Q fragments (B operand 32x32x16): col=q=lane&31, k=(lane>>5)*8+e; pre-scaled
    short8 qfA[4], qfB[4];
    {
        const unsigned short* qrowA = Qb + (size_t)(q0 + w * 64 + l31) * HD + half * 8;
        const unsigned short* qrowB = qrowA + 32 * HD;
#pragma unroll
        for (int ks = 0; ks < 4; ++ks) {
            qfA[ks] = *(const short8*)(qrowA + ks * 16);
            qfB[ks] = *(const short8*)(qrowB + ks * 16);
        }
    }

    floatx16 oaccA[2], oaccB[2];   // O^T: col=q=lane&31, row=hd_local=(reg&3)+8*(reg>>2)+4*half
#pragma unroll
    for (int ht = 0; ht < 2; ++ht)
#pragma unroll
        for (int i = 0; i < 16; ++i) { oaccA[ht][i] = 0.f; oaccB[ht][i] = 0.f; }
    float lA = 0.f, lB = 0.f;

    // staging: 8 thread-chunks x 64 lanes x 16B = 8KB per subtile (K and V)
    const unsigned short* gk[2]; const unsigned short* gv[2];
    unsigned short* lk[2][2];    unsigned short* lv[2][2];
#pragma unroll
    for (int i = 0; i < 2; ++i) {
        int off = (((w * 2 + i) << 6) + lane) * 8;
        gk[i] = Kb + off;
        gv[i] = Vb + off;
#pragma unroll
        for (int b = 0; b < 2; ++b) {
            lk[b][i] = &Ks[b][(w * 2 + i) << 9];
            lv[b][i] = &Vs[b][(w * 2 + i) << 9];
        }
    }

    // prologue: DMA subtile 0 into buffer 0
#pragma unroll
    for (int i = 0; i < 2; ++i) {
        __builtin_amdgcn_global_load_lds((GV*)(void*)gk[i], (LV*)(void*)lk[0][i], 16, 0, 0);
        __builtin_amdgcn_global_load_lds((GV*)(void*)gv[i], (LV*)(void*)lv[0][i], 16, 0, 0);
    }

    for (int t = 0; t < 32; ++t) {
        const int buf = t & 1;
        __syncthreads();
        if (t < 31) {
#pragma unroll
            for (int i = 0; i < 2; ++i) {
                __builtin_amdgcn_global_load_lds((GV*)(void*)(gk[i] + (t + 1) * 4096), (LV*)(void*)lk[buf ^ 1][i], 16, 0, 0);
                __builtin_amdgcn_global_load_lds((GV*)(void*)(gv[i] + (t + 1) * 4096), (LV*)(void*)lv[buf ^ 1][i], 16, 0, 0);
            }
        }
        const unsigned short* KsB = Ks[buf];
        const unsigned short* VsB = Vs[buf];

#pragma unroll
        for (int kt = 0; kt < 2; ++kt) {
            // ---- S^T(32k x 32q) over hd=64, both q-tiles share each K read
            floatx16 sA, sB;
#pragma unroll
            for (int i = 0; i < 16; ++i) { sA[i] = 0.f; sB[i] = 0.f; }
            __builtin_amdgcn_s_setprio(1);
#pragma unroll
            for (int ks = 0; ks < 4; ++ks) {
                short8 kf = *(const short8*)(KsB + ((kt * 4 + ks) << 9) + lane * 8);
                sA = __builtin_amdgcn_mfma_f32_32x32x16_bf16(kf, qfA[ks], sA, 0, 0, 0);
                sB = __builtin_amdgcn_mfma_f32_32x32x16_bf16(kf, qfB[ks], sB, 0, 0, 0);
            }
            __builtin_amdgcn_s_setprio(0);

            // ---- softmax A and B (independent -> VALU ILP): exp2, f16 pack,
            //      l via v_dot2_f32_f16 on packed pairs, half-swap to B-frags
            half8 pA0, pA1, pB0, pB1;
            {
                fp16x2 ones; ones[0] = (__fp16)1.0f; ones[1] = (__fp16)1.0f;
                unsigned int ua[8], ub[8];
#pragma unroll
                for (int j = 0; j < 8; ++j) {
                    fp16x2 pa = __builtin_amdgcn_cvt_pkrtz(ex2(sA[2 * j]), ex2(sA[2 * j + 1]));
                    fp16x2 pb = __builtin_amdgcn_cvt_pkrtz(ex2(sB[2 * j]), ex2(sB[2 * j + 1]));
                    ua[j] = __builtin_bit_cast(unsigned int, pa);
                    ub[j] = __builtin_bit_cast(unsigned int, pb);
#if __has_builtin(__builtin_amdgcn_fdot2)
                    lA = __builtin_amdgcn_fdot2(pa, ones, lA, false);
                    lB = __builtin_amdgcn_fdot2(pb, ones, lB, false);
#else
                    lA += (float)pa[0] + (float)pa[1];
                    lB += (float)pb[0] + (float)pb[1];
#endif
                }
                pl32swap(ua[0], ua[2]); pl32swap(ua[1], ua[3]);
                pl32swap(ua[4], ua[6]); pl32swap(ua[5], ua[7]);
                pl32swap(ub[0], ub[2]); pl32swap(ub[1], ub[3]);
                pl32swap(ub[4], ub[6]); pl32swap(ub[5], ub[7]);
                uint4v t0, t1, t2, t3;
                t0.x = ua[0]; t0.y = ua[1]; t0.z = ua[2]; t0.w = ua[3];
                t1.x = ua[4]; t1.y = ua[5]; t1.z = ua[6]; t1.w = ua[7];
                t2.x = ub[0]; t2.y = ub[1]; t2.z = ub[2]; t2.w = ub[3];
                t3.x = ub[4]; t3.y = ub[5]; t3.z = ub[6]; t3.w = ub[7];
                pA0 = __builtin_bit_cast(half8, t0);
                pA1 = __builtin_bit_cast(half8, t1);
                pB0 = __builtin_bit_cast(half8, t2);
                pB1 = __builtin_bit_cast(half8, t3);
            }

            // ---- PV: O^T += V^T * P^T, both q-tiles share each V read
            __builtin_amdgcn_s_setprio(1);
#pragma unroll
            for (int ht = 0; ht < 2; ++ht) {
                uint4v v0 = *(const uint4v*)(VsB + (((ht << 2) + kt * 2) << 9) + lane * 8);
                uint4v v1 = *(const uint4v*)(VsB + (((ht << 2) + kt * 2 + 1) << 9) + lane * 8);
                half8 vf0 = __builtin_bit_cast(half8, v0);
                half8 vf1 = __builtin_bit_cast(half8, v1);
                oaccA[ht] = __builtin_amdgcn_mfma_f32_32x32x16_f16(vf0, pA0, oaccA[ht], 0, 0, 0);
                oaccB[ht] = __builtin_amdgcn_mfma_f32_32x32x16_f16(vf0, pB0, oaccB[ht], 0, 0, 0);
                oaccA[ht] = __builtin_amdgcn_mfma_f32_32x32x16_f16(vf1, pA1, oaccA[ht], 0, 0, 0);
                oaccB[ht] = __builtin_amdgcn_mfma_f32_32x32x16_f16(vf1, pB1, oaccB[ht], 0, 0, 0);
            }
            __builtin_amdgcn_s_setprio(0);
        }
    }

    // ---- epilogue: l across lane halves, O /= l, write bf16 (both tiles)
    const int b = bh >> 4, h = bh & 15;
#pragma unroll
    for (int tile = 0; tile < 2; ++tile) {
        float lfull = tile == 0 ? lA : lB;
        lfull += __shfl_xor(lfull, 32);
        float inv = 1.f / lfull;
        const floatx16* oc = tile == 0 ? oaccA : oaccB;
        const int qg = q0 + w * 64 + tile * 32 + l31;
        unsigned short* orow = ob + ((size_t)b * SEQ + qg) * NDIM + h * HD;
#pragma unroll
        for (int ht = 0; ht < 2; ++ht) {
#pragma unroll
            for (int g = 0; g < 4; ++g) {
                int hd0 = ht * 32 + g * 8 + half * 4;
                unsigned int w0 = (unsigned int)f2bf(oc[ht][g * 4 + 0] * inv)
                                | ((unsigned int)f2bf(oc[ht][g * 4 + 1] * inv) << 16);
                unsigned int w1 = (unsigned int)f2bf(oc[ht][g * 4 + 2] * inv)
                                | ((unsigned int)f2bf(oc[ht][g * 4 + 3] * inv) << 16);
                uint2v st; st.x = w0; st.y = w1;
                *(uint2v*)(orow + hd0) = st;
            }
        }
    }
}

// ---------------------------------------------------------------- launch
extern "C" void kernel_launch(void* const* d_in, const int* in_sizes, int n_in,
                              void* d_out, int out_size, void* d_ws, size_t ws_size,
                              hipStream_t stream)
{
    (void)in_sizes; (void)n_in; (void)out_size; (void)ws_size;
    const float* x    = (const float*)d_in[0];
    const float* wqkv = (const float*)d_in[1];
    const float* wout = (const float*)d_in[2];
    const float* bout = (const float*)d_in[3];
    float* out = (float*)d_out;

    unsigned short* xb    = (unsigned short*)d_ws;
    unsigned short* wqkvb = xb    + 8388608;
    unsigned short* woutb = wqkvb + 3145728;
    unsigned short* qbuf  = woutb + 1048576;
    unsigned short* kbuf  = qbuf  + 8388608;
    unsigned short* vbuf  = kbuf  + 8388608;
    unsigned short* obuf  = vbuf  + 8388608;

    cast_f32_bf16<<<8192, 256, 0, stream>>>(x, xb);
    cast_f32_bf16<<<3072, 256, 0, stream>>>(wqkv, wqkvb);
    cast_f32_bf16<<<1024, 256, 0, stream>>>(wout, woutb);

    gemm_bt<0><<<dim3(64, 24), 256, 0, stream>>>(xb, wqkvb, qbuf, kbuf, vbuf, nullptr, nullptr);
    attn_fused<<<512, 256, 0, stream>>>(qbuf, kbuf, vbuf, obuf);
    gemm_bt<1><<<dim3(64, 8), 256, 0, stream>>>(obuf, woutb, nullptr, nullptr, nullptr, bout, out);
}